// Round 1
// baseline (346.183 us; speedup 1.0000x reference)
//
#include <hip/hip_runtime.h>

// upfirdn2d(x, k, up=2, down=1, pad=(2,1)), k = outer([1,3,3,1])/16.
// Separable per-axis (weights [1,3,3,1]/4 on zero-stuffed input):
//   out[2r]   = 0.25*in[r-1] + 0.75*in[r]
//   out[2r+1] = 0.75*in[r]   + 0.25*in[r+1]
// x: (16,256,64,64) f32 -> out: (16,256,128,128) f32.
//
// Each thread: 4 output rows x 8 output cols (input cols 4q..4q+3, rows 2t..2t+1).
// Loads 4 input rows (2t-1..2t+2) as one aligned float4 each (dwordx4).
// Vertical filter FIRST (on float4 vectors, per-lane independent), then the
// horizontal filter per output row; +-1-column halos come from neighbor lanes
// via shfl. Lanes where the shfl crosses the 16-lane group seam (q==0 left,
// q==15 right) are exactly the boundary-zero lanes, so the wrong-group pull
// is masked anyway. Output stores are nontemporal (never re-read; keep L3
// for the 64 MiB input, which is re-read ~2x for row halos).

typedef float f32x4 __attribute__((ext_vector_type(4)));

__global__ __launch_bounds__(256) void upsample_2x_kernel(
    const float* __restrict__ x, float* __restrict__ out) {
  int idx = blockIdx.x * 256 + threadIdx.x;
  int q   = idx & 15;         // col group: input cols 4q..4q+3 -> output cols 8q..8q+7
  int t   = (idx >> 4) & 31;  // row pair: input rows 2t,2t+1 -> output rows 4t..4t+3
  int img = idx >> 9;         // B*C image (16*32 = 512 threads/img)

  const float* xi = x + (size_t)img * (64 * 64);
  float*       oi = out + (size_t)img * (128 * 128);

  const int c  = 4 * q;
  const int r0 = 2 * t;
  const float* xr = xi + r0 * 64 + c;

  const float4 z = make_float4(0.f, 0.f, 0.f, 0.f);
  // 4 input rows: r0-1, r0, r0+1, r0+2 (zero outside [0,64))
  float4 m0 = (t > 0)  ? *(const float4*)(xr - 64)  : z;
  float4 m1 =            *(const float4*)(xr);
  float4 m2 =            *(const float4*)(xr + 64);
  float4 m3 = (t < 31) ? *(const float4*)(xr + 128) : z;

  // Vertical pass on float4 lanes -> 4 output rows (cols c..c+3 pre-upsample).
  float4 v[4];
#define VMIX(d, a, b, wa, wb)                                   \
  d.x = wa * a.x + wb * b.x; d.y = wa * a.y + wb * b.y;         \
  d.z = wa * a.z + wb * b.z; d.w = wa * a.w + wb * b.w;
  VMIX(v[0], m0, m1, 0.25f, 0.75f)   // out row 4t   (even, r=r0)
  VMIX(v[1], m1, m2, 0.75f, 0.25f)   // out row 4t+1 (odd,  r=r0)
  VMIX(v[2], m1, m2, 0.25f, 0.75f)   // out row 4t+2 (even, r=r0+1)
  VMIX(v[3], m2, m3, 0.75f, 0.25f)   // out row 4t+3 (odd,  r=r0+1)
#undef VMIX

  // Horizontal pass per output row: cols (c-1 .. c+4) -> output cols 8q..8q+7.
  float* op = oi + (4 * t) * 128 + 8 * q;
#pragma unroll
  for (int j = 0; j < 4; ++j) {
    float left  = __shfl_up(v[j].w, 1);   // lane q-1's col c-1 (post-vertical)
    float right = __shfl_down(v[j].x, 1); // lane q+1's col c+4 (post-vertical)
    if (q == 0)  left  = 0.f;
    if (q == 15) right = 0.f;
    f32x4 e0, e1;
    e0[0] = 0.25f * left   + 0.75f * v[j].x;  // col 8q   (even)
    e0[1] = 0.75f * v[j].x + 0.25f * v[j].y;  // col 8q+1 (odd)
    e0[2] = 0.25f * v[j].x + 0.75f * v[j].y;  // col 8q+2 (even)
    e0[3] = 0.75f * v[j].y + 0.25f * v[j].z;  // col 8q+3 (odd)
    e1[0] = 0.25f * v[j].y + 0.75f * v[j].z;  // col 8q+4 (even)
    e1[1] = 0.75f * v[j].z + 0.25f * v[j].w;  // col 8q+5 (odd)
    e1[2] = 0.25f * v[j].z + 0.75f * v[j].w;  // col 8q+6 (even)
    e1[3] = 0.75f * v[j].w + 0.25f * right;   // col 8q+7 (odd)
    __builtin_nontemporal_store(e0, (f32x4*)(op + j * 128));
    __builtin_nontemporal_store(e1, (f32x4*)(op + j * 128 + 4));
  }
}

extern "C" void kernel_launch(void* const* d_in, const int* in_sizes, int n_in,
                              void* d_out, int out_size, void* d_ws, size_t ws_size,
                              hipStream_t stream) {
  const float* x = (const float*)d_in[0];
  float* out = (float*)d_out;
  // 16*256 images * 32 row-pairs * 16 col-groups = 2,097,152 threads
  const int blocks = (16 * 256 * 32 * 16) / 256;  // 8192
  upsample_2x_kernel<<<blocks, 256, 0, stream>>>(x, out);
}

// Round 2
// 325.976 us; speedup vs baseline: 1.0620x; 1.0620x over previous
//
#include <hip/hip_runtime.h>

// upfirdn2d(x, k, up=2, down=1, pad=(2,1)), k = outer([1,3,3,1])/16.
// Separable per-axis (weights [1,3,3,1]/4 on zero-stuffed input):
//   out[2r]   = 0.25*in[r-1] + 0.75*in[r]
//   out[2r+1] = 0.75*in[r]   + 0.25*in[r+1]
// x: (16,256,64,64) f32 -> out: (16,256,128,128) f32.
//
// Each thread: 4 output rows x 8 output cols (input cols 4q..4q+3, rows 2t..2t+1).
// Loads 4 input rows (2t-1..2t+2) as one aligned float4 each (dwordx4).
// Vertical filter FIRST (on float4 vectors, per-lane independent), then the
// horizontal filter per output row; +-1-column halos come from neighbor lanes
// via shfl. Lanes where the shfl crosses the 16-lane group seam (q==0 left,
// q==15 right) are exactly the boundary-zero lanes, so the wrong-group pull
// is masked anyway.
//
// Stores are PLAIN (not nontemporal): each lane's two 16B stores are
// half-line strided (32B lane stride); they must merge in L2 into full
// lines before writeback. Round-1's nontemporal stores defeated that merge
// (partial-line HBM writes -> RMW), costing +36us on the 256MiB output.

typedef float f32x4 __attribute__((ext_vector_type(4)));

__global__ __launch_bounds__(256) void upsample_2x_kernel(
    const float* __restrict__ x, float* __restrict__ out) {
  int idx = blockIdx.x * 256 + threadIdx.x;
  int q   = idx & 15;         // col group: input cols 4q..4q+3 -> output cols 8q..8q+7
  int t   = (idx >> 4) & 31;  // row pair: input rows 2t,2t+1 -> output rows 4t..4t+3
  int img = idx >> 9;         // B*C image (16*32 = 512 threads/img)

  const float* xi = x + (size_t)img * (64 * 64);
  float*       oi = out + (size_t)img * (128 * 128);

  const int c  = 4 * q;
  const int r0 = 2 * t;
  const float* xr = xi + r0 * 64 + c;

  const float4 z = make_float4(0.f, 0.f, 0.f, 0.f);
  // 4 input rows: r0-1, r0, r0+1, r0+2 (zero outside [0,64))
  float4 m0 = (t > 0)  ? *(const float4*)(xr - 64)  : z;
  float4 m1 =            *(const float4*)(xr);
  float4 m2 =            *(const float4*)(xr + 64);
  float4 m3 = (t < 31) ? *(const float4*)(xr + 128) : z;

  // Vertical pass on float4 lanes -> 4 output rows (cols c..c+3 pre-upsample).
  float4 v[4];
#define VMIX(d, a, b, wa, wb)                                   \
  d.x = wa * a.x + wb * b.x; d.y = wa * a.y + wb * b.y;         \
  d.z = wa * a.z + wb * b.z; d.w = wa * a.w + wb * b.w;
  VMIX(v[0], m0, m1, 0.25f, 0.75f)   // out row 4t   (even, r=r0)
  VMIX(v[1], m1, m2, 0.75f, 0.25f)   // out row 4t+1 (odd,  r=r0)
  VMIX(v[2], m1, m2, 0.25f, 0.75f)   // out row 4t+2 (even, r=r0+1)
  VMIX(v[3], m2, m3, 0.75f, 0.25f)   // out row 4t+3 (odd,  r=r0+1)
#undef VMIX

  // Horizontal pass per output row: cols (c-1 .. c+4) -> output cols 8q..8q+7.
  float* op = oi + (4 * t) * 128 + 8 * q;
#pragma unroll
  for (int j = 0; j < 4; ++j) {
    float left  = __shfl_up(v[j].w, 1);   // lane q-1's col c-1 (post-vertical)
    float right = __shfl_down(v[j].x, 1); // lane q+1's col c+4 (post-vertical)
    if (q == 0)  left  = 0.f;
    if (q == 15) right = 0.f;
    f32x4 e0, e1;
    e0[0] = 0.25f * left   + 0.75f * v[j].x;  // col 8q   (even)
    e0[1] = 0.75f * v[j].x + 0.25f * v[j].y;  // col 8q+1 (odd)
    e0[2] = 0.25f * v[j].x + 0.75f * v[j].y;  // col 8q+2 (even)
    e0[3] = 0.75f * v[j].y + 0.25f * v[j].z;  // col 8q+3 (odd)
    e1[0] = 0.25f * v[j].y + 0.75f * v[j].z;  // col 8q+4 (even)
    e1[1] = 0.75f * v[j].z + 0.25f * v[j].w;  // col 8q+5 (odd)
    e1[2] = 0.25f * v[j].z + 0.75f * v[j].w;  // col 8q+6 (even)
    e1[3] = 0.75f * v[j].w + 0.25f * right;   // col 8q+7 (odd)
    *(f32x4*)(op + j * 128)     = e0;
    *(f32x4*)(op + j * 128 + 4) = e1;
  }
}

extern "C" void kernel_launch(void* const* d_in, const int* in_sizes, int n_in,
                              void* d_out, int out_size, void* d_ws, size_t ws_size,
                              hipStream_t stream) {
  const float* x = (const float*)d_in[0];
  float* out = (float*)d_out;
  // 16*256 images * 32 row-pairs * 16 col-groups = 2,097,152 threads
  const int blocks = (16 * 256 * 32 * 16) / 256;  // 8192
  upsample_2x_kernel<<<blocks, 256, 0, stream>>>(x, out);
}

// Round 3
// 312.603 us; speedup vs baseline: 1.1074x; 1.0428x over previous
//
#include <hip/hip_runtime.h>

// upfirdn2d(x, k, up=2, down=1, pad=(2,1)), k = outer([1,3,3,1])/16.
// Separable per-axis (weights [1,3,3,1]/4 on zero-stuffed input):
//   out[2r]   = 0.25*in[r-1] + 0.75*in[r]
//   out[2r+1] = 0.75*in[r]   + 0.25*in[r+1]
// x: (16,256,64,64) f32 -> out: (16,256,128,128) f32.
//
// Persistent column-strip walk ("fill-shaped" kernel):
// each thread owns input cols 2q..2q+1 of a 16-row strip of one image and
// walks down, keeping a rolling window of 3 horizontally-filtered rows
// (H[r-1], H[r], H[r+1], each float4 = output cols 4q..4q+3). Per step:
//   1 float2 load (next input row), 2 shfl (col halos), ~20 VALU,
//   2 fully lane-contiguous float4 stores (output rows 2r, 2r+1).
// Rationale vs the 4x4/4x8-tile versions:
//  - stores: 32 lanes x 16B contiguous per instruction (r2's 32B-stride
//    half-line pattern cost ~10%);
//  - each input row is read ONCE (tile versions re-read halo rows 2x);
//  - long per-wave store streams + fully-unrolled loop -> loads hoisted
//    many rows ahead (MLP), like the 80%-of-peak fill kernel, instead of
//    65K short-lived waves each stalling on 4 dependent cold loads.
// Lanes 32..63 of a wave are a different strip; the width-64 shfl that
// crosses the lane-31/32 seam is pulled only by q==0/q==31 lanes, which
// are exactly the boundary-zero lanes, so the wrong-strip value is masked.

typedef float f32x4 __attribute__((ext_vector_type(4)));

#define STRIP 16  // input rows per thread-strip (4 strips per 64-row image)

__global__ __launch_bounds__(256) void upsample_2x_kernel(
    const float* __restrict__ x, float* __restrict__ out) {
  int idx = blockIdx.x * 256 + threadIdx.x;
  int q   = idx & 31;   // col pair: input cols 2q,2q+1 -> output cols 4q..4q+3
  int u   = idx >> 5;   // strip unit
  int s   = u & 3;      // strip within image
  int img = u >> 2;     // B*C image

  const float* xi = x + (size_t)img * (64 * 64) + 2 * q;
  float*       oi = out + (size_t)img * (128 * 128) + 4 * q;

  const int rs = s * STRIP;

  auto loadrow = [&](int r) -> float2 {
    return (r >= 0 && r < 64) ? *(const float2*)(xi + r * 64)
                              : make_float2(0.f, 0.f);
  };
  // Horizontal pass on one input row -> output cols 4q..4q+3 (pre-vertical).
  auto horiz = [&](float2 m) -> f32x4 {
    float left  = __shfl_up(m.y, 1);    // lane q-1's col 2q-1
    float right = __shfl_down(m.x, 1);  // lane q+1's col 2q+2
    if (q == 0)  left  = 0.f;
    if (q == 31) right = 0.f;
    float a = 0.75f * m.x, b = 0.75f * m.y;
    f32x4 h;
    h[0] = a + 0.25f * left;   // col 4q   (even)
    h[1] = a + 0.25f * m.y;    // col 4q+1 (odd)
    h[2] = b + 0.25f * m.x;    // col 4q+2 (even)
    h[3] = b + 0.25f * right;  // col 4q+3 (odd)
    return h;
  };

  f32x4 Hm1 = horiz(loadrow(rs - 1));  // H[rs-1] (zero row if rs==0)
  f32x4 H0  = horiz(loadrow(rs));      // H[rs]
  f32x4 c   = 0.75f * H0;              // shared center term

  float* op = oi + (2 * rs) * 128;

#pragma unroll
  for (int i = 0; i < STRIP; ++i) {
    const int r = rs + i;
    f32x4 H1 = horiz(loadrow(r + 1));  // H[r+1] (zero row past 63)
    f32x4 o0 = c + 0.25f * Hm1;        // out[2r]   = 0.25*H[r-1] + 0.75*H[r]
    f32x4 o1 = c + 0.25f * H1;         // out[2r+1] = 0.75*H[r] + 0.25*H[r+1]
    *(f32x4*)(op)       = o0;
    *(f32x4*)(op + 128) = o1;
    op += 256;
    Hm1 = H0;
    H0  = H1;
    c   = 0.75f * H1;
  }
}

extern "C" void kernel_launch(void* const* d_in, const int* in_sizes, int n_in,
                              void* d_out, int out_size, void* d_ws, size_t ws_size,
                              hipStream_t stream) {
  const float* x = (const float*)d_in[0];
  float* out = (float*)d_out;
  // 16*256 images * 4 strips * 32 col-pairs = 524,288 threads
  const int blocks = (16 * 256 * 4 * 32) / 256;  // 2048
  upsample_2x_kernel<<<blocks, 256, 0, stream>>>(x, out);
}

// Round 4
// 306.462 us; speedup vs baseline: 1.1296x; 1.0200x over previous
//
#include <hip/hip_runtime.h>

// upfirdn2d(x, k, up=2, down=1, pad=(2,1)), k = outer([1,3,3,1])/16.
// Separable per-axis (weights [1,3,3,1]/4 on zero-stuffed input):
//   out[2r]   = 0.25*in[r-1] + 0.75*in[r]
//   out[2r+1] = 0.75*in[r]   + 0.25*in[r+1]
// x: (16,256,64,64) f32 -> out: (16,256,128,128) f32.
//
// Persistent column-strip walk, identical to round 3 EXCEPT the stores are
// nontemporal. Round-3 finding: three structurally different kernels all
// plateau at ~144us kernel time (~2.3 TB/s) while the harness fill hits
// 6.3 TB/s on the same buffer -> suspected read-for-ownership on the output
// write stream (268MB extra HBM reads). Store pattern here is fully
// line-aligned (each store: two 512B contiguous half-wave segments,
// sequential rows per wave), so nt cannot cause partial-line HBM writes
// (round-1's nt regression was nt x strided-half-line stores).

typedef float f32x4 __attribute__((ext_vector_type(4)));

#define STRIP 16  // input rows per thread-strip (4 strips per 64-row image)

__global__ __launch_bounds__(256) void upsample_2x_kernel(
    const float* __restrict__ x, float* __restrict__ out) {
  int idx = blockIdx.x * 256 + threadIdx.x;
  int q   = idx & 31;   // col pair: input cols 2q,2q+1 -> output cols 4q..4q+3
  int u   = idx >> 5;   // strip unit
  int s   = u & 3;      // strip within image
  int img = u >> 2;     // B*C image

  const float* xi = x + (size_t)img * (64 * 64) + 2 * q;
  float*       oi = out + (size_t)img * (128 * 128) + 4 * q;

  const int rs = s * STRIP;

  auto loadrow = [&](int r) -> float2 {
    return (r >= 0 && r < 64) ? *(const float2*)(xi + r * 64)
                              : make_float2(0.f, 0.f);
  };
  // Horizontal pass on one input row -> output cols 4q..4q+3 (pre-vertical).
  auto horiz = [&](float2 m) -> f32x4 {
    float left  = __shfl_up(m.y, 1);    // lane q-1's col 2q-1
    float right = __shfl_down(m.x, 1);  // lane q+1's col 2q+2
    if (q == 0)  left  = 0.f;
    if (q == 31) right = 0.f;
    float a = 0.75f * m.x, b = 0.75f * m.y;
    f32x4 h;
    h[0] = a + 0.25f * left;   // col 4q   (even)
    h[1] = a + 0.25f * m.y;    // col 4q+1 (odd)
    h[2] = b + 0.25f * m.x;    // col 4q+2 (even)
    h[3] = b + 0.25f * right;  // col 4q+3 (odd)
    return h;
  };

  f32x4 Hm1 = horiz(loadrow(rs - 1));  // H[rs-1] (zero row if rs==0)
  f32x4 H0  = horiz(loadrow(rs));      // H[rs]
  f32x4 c   = 0.75f * H0;              // shared center term

  float* op = oi + (2 * rs) * 128;

#pragma unroll
  for (int i = 0; i < STRIP; ++i) {
    const int r = rs + i;
    f32x4 H1 = horiz(loadrow(r + 1));  // H[r+1] (zero row past 63)
    f32x4 o0 = c + 0.25f * Hm1;        // out[2r]   = 0.25*H[r-1] + 0.75*H[r]
    f32x4 o1 = c + 0.25f * H1;         // out[2r+1] = 0.75*H[r] + 0.25*H[r+1]
    __builtin_nontemporal_store(o0, (f32x4*)(op));
    __builtin_nontemporal_store(o1, (f32x4*)(op + 128));
    op += 256;
    Hm1 = H0;
    H0  = H1;
    c   = 0.75f * H1;
  }
}

extern "C" void kernel_launch(void* const* d_in, const int* in_sizes, int n_in,
                              void* d_out, int out_size, void* d_ws, size_t ws_size,
                              hipStream_t stream) {
  const float* x = (const float*)d_in[0];
  float* out = (float*)d_out;
  // 16*256 images * 4 strips * 32 col-pairs = 524,288 threads
  const int blocks = (16 * 256 * 4 * 32) / 256;  // 2048
  upsample_2x_kernel<<<blocks, 256, 0, stream>>>(x, out);
}

// Round 5
// 303.635 us; speedup vs baseline: 1.1401x; 1.0093x over previous
//
#include <hip/hip_runtime.h>

// upfirdn2d(x, k, up=2, down=1, pad=(2,1)), k = outer([1,3,3,1])/16.
// Separable per-axis (weights [1,3,3,1]/4 on zero-stuffed input):
//   out[2r]   = 0.25*in[r-1] + 0.75*in[r]
//   out[2r+1] = 0.75*in[r]   + 0.25*in[r+1]
// x: (16,256,64,64) f32 -> out: (16,256,128,128) f32.
//
// Phase-separated strip kernel (round-5 experiment: read/write stream
// de-mixing). Each thread owns input cols 2q..2q+1 of a 16-row strip:
//   READ PHASE : all 18 halo-inclusive rows loaded in one burst
//                (18x global_load_dwordx2, 36 VGPR) -> single long read
//                run per wave, max memory-level parallelism.
//   WRITE PHASE: 32 nontemporal float4 stores back-to-back (only
//                VALU/shfl between them) -> one sequential 16KB write
//                run per half-wave, no interleaved loads.
// Prior rounds alternated load-row/store-2-rows, so DRAM saw fine-grained
// read<->write turnaround; the 80%-peak harness fill is pure-write.
// Stores stay nontemporal (round-4: +6us, keeps 67MB input L3-resident
// across iterations instead of being evicted by the 268MB output stream).
// Lanes 32..63 are a different strip; the width-64 shfl crossing the
// lane-31/32 seam is pulled only by q==0/q==31 lanes, which are exactly
// the boundary-zero lanes, so the wrong-strip value is masked.

typedef float f32x4 __attribute__((ext_vector_type(4)));

#define STRIP 16  // input rows per thread-strip (4 strips per 64-row image)

__global__ __launch_bounds__(256) void upsample_2x_kernel(
    const float* __restrict__ x, float* __restrict__ out) {
  int idx = blockIdx.x * 256 + threadIdx.x;
  int q   = idx & 31;   // col pair: input cols 2q,2q+1 -> output cols 4q..4q+3
  int u   = idx >> 5;   // strip unit
  int s   = u & 3;      // strip within image
  int img = u >> 2;     // B*C image

  const float* xi = x + (size_t)img * (64 * 64) + 2 * q;
  float*       oi = out + (size_t)img * (128 * 128) + 4 * q;

  const int rs = s * STRIP;

  // ---- READ PHASE: rows rs-1 .. rs+STRIP (18 rows), one load burst. ----
  float2 m[STRIP + 2];
  m[0] = (s > 0) ? *(const float2*)(xi + (rs - 1) * 64) : make_float2(0.f, 0.f);
#pragma unroll
  for (int i = 0; i < STRIP; ++i)
    m[1 + i] = *(const float2*)(xi + (rs + i) * 64);
  m[STRIP + 1] =
      (s < 3) ? *(const float2*)(xi + (rs + STRIP) * 64) : make_float2(0.f, 0.f);

  // Horizontal pass on one input row -> output cols 4q..4q+3 (pre-vertical).
  auto horiz = [&](float2 v) -> f32x4 {
    float left  = __shfl_up(v.y, 1);    // lane q-1's col 2q-1
    float right = __shfl_down(v.x, 1);  // lane q+1's col 2q+2
    if (q == 0)  left  = 0.f;
    if (q == 31) right = 0.f;
    float a = 0.75f * v.x, b = 0.75f * v.y;
    f32x4 h;
    h[0] = a + 0.25f * left;   // col 4q   (even)
    h[1] = a + 0.25f * v.y;    // col 4q+1 (odd)
    h[2] = b + 0.25f * v.x;    // col 4q+2 (even)
    h[3] = b + 0.25f * right;  // col 4q+3 (odd)
    return h;
  };

  // ---- WRITE PHASE: 32 sequential nt stores, rolling 3-row H window. ----
  f32x4 Hm1 = horiz(m[0]);
  f32x4 H0  = horiz(m[1]);
  float* op = oi + (2 * rs) * 128;

#pragma unroll
  for (int i = 0; i < STRIP; ++i) {
    f32x4 H1 = horiz(m[i + 2]);
    f32x4 c  = 0.75f * H0;             // shared center term
    f32x4 o0 = c + 0.25f * Hm1;        // out[2r]   = 0.25*H[r-1] + 0.75*H[r]
    f32x4 o1 = c + 0.25f * H1;         // out[2r+1] = 0.75*H[r] + 0.25*H[r+1]
    __builtin_nontemporal_store(o0, (f32x4*)(op));
    __builtin_nontemporal_store(o1, (f32x4*)(op + 128));
    op += 256;
    Hm1 = H0;
    H0  = H1;
  }
}

extern "C" void kernel_launch(void* const* d_in, const int* in_sizes, int n_in,
                              void* d_out, int out_size, void* d_ws, size_t ws_size,
                              hipStream_t stream) {
  const float* x = (const float*)d_in[0];
  float* out = (float*)d_out;
  // 16*256 images * 4 strips * 32 col-pairs = 524,288 threads
  const int blocks = (16 * 256 * 4 * 32) / 256;  // 2048
  upsample_2x_kernel<<<blocks, 256, 0, stream>>>(x, out);
}